// Round 1
// baseline (327.690 us; speedup 1.0000x reference)
//
#include <hip/hip_runtime.h>
#include <hip/hip_bf16.h>

typedef __hip_bfloat16 bf16;
typedef __attribute__((ext_vector_type(4))) float f32x4;
typedef __attribute__((ext_vector_type(8))) unsigned short u16x8;
typedef __attribute__((ext_vector_type(4))) unsigned short u16x4;
typedef __bf16 bf16x8 __attribute__((ext_vector_type(8)));

#define NNODES 169
#define NNTOT  338
#define CH     256
#define NH     4
#define NL     3
#define SPAD   176
#define LN_EPS 1e-5f

__device__ __forceinline__ float b2f(bf16 v) { return __bfloat162float(v); }
__device__ __forceinline__ float lrelu(float v) { return fmaxf(v, 0.2f * v); }
__device__ __forceinline__ float ldm(const void* p, size_t i, int isbf) {
    return isbf ? b2f(((const bf16*)p)[i]) : ((const float*)p)[i];
}
__device__ __forceinline__ int sniff_bf(const void* lng) {
    return ((((const unsigned*)lng)[0] & 0xFFFFu) == 0x3F80u) ? 1 : 0;
}
// round-to-nearest-even f32 -> bf16 bits
__device__ __forceinline__ unsigned short f2bf_rn(float f) {
    unsigned u = __float_as_uint(f);
    u += 0x7FFFu + ((u >> 16) & 1u);
    return (unsigned short)(u >> 16);
}
__device__ __forceinline__ float bfb2f(unsigned short h) {
    return __uint_as_float(((unsigned)h) << 16);
}

// ---------------------------------------------------------------- W prep
// Transpose + bf16-hi/lo split of all weights, once per launch.
// Output layout per family: hi plane [L][N][K] then lo plane [L][N][K] (bf16 bits).
// Tile 64k x 64n per block. Grid: Wl [0,192) Wr [192,384) W1 [384,480) W2 [480,576).
__global__ __launch_bounds__(256) void k_wprep(
    const void* __restrict__ Wl, const void* __restrict__ Wr,
    const void* __restrict__ W1, const void* __restrict__ W2,
    unsigned short* __restrict__ wlT, unsigned short* __restrict__ wrT,
    unsigned short* __restrict__ w1T, unsigned short* __restrict__ w2T,
    const void* __restrict__ lng)
{
    __shared__ unsigned short sH[64 * 72];
    __shared__ unsigned short sL[64 * 72];
    const int isbf = sniff_bf(lng);
    int t = blockIdx.x;
    const void* src; unsigned short* dst; int K, N;
    if (t < 384)      { K = 256; N = 1024; src = (t < 192) ? Wl : Wr;
                        dst = (t < 192) ? wlT : wrT; t = t % 192; }
    else if (t < 480) { K = 256; N = 512;  src = W1; dst = w1T; t -= 384; }
    else              { K = 512; N = 256;  src = W2; dst = w2T; t -= 480; }
    const int ntiles = N / 64;
    const int tpl = (K / 64) * ntiles;
    const int l = t / tpl; t %= tpl;
    const int k0 = (t / ntiles) * 64, n0 = (t % ntiles) * 64;
    const size_t loPlane = (size_t)NL * K * N;
    const int tid = threadIdx.x;

    // stage: thread reads row kk, 4 interleaved float4-chunks (coalesced in 64B units)
    const int kk = tid >> 2, q = tid & 3;
    if (isbf) {
        const bf16* srow = (const bf16*)src + ((size_t)l * K + k0 + kk) * N + n0;
        #pragma unroll
        for (int i = 0; i < 4; i++) {
            const int c = q * 4 + i * 16;
            const int2 w = *(const int2*)(srow + c);
            const unsigned short u0 = (unsigned short)(w.x & 0xFFFF);
            const unsigned short u1 = (unsigned short)(((unsigned)w.x) >> 16);
            const unsigned short u2 = (unsigned short)(w.y & 0xFFFF);
            const unsigned short u3 = (unsigned short)(((unsigned)w.y) >> 16);
            sH[kk * 72 + c + 0] = u0; sL[kk * 72 + c + 0] = 0;
            sH[kk * 72 + c + 1] = u1; sL[kk * 72 + c + 1] = 0;
            sH[kk * 72 + c + 2] = u2; sL[kk * 72 + c + 2] = 0;
            sH[kk * 72 + c + 3] = u3; sL[kk * 72 + c + 3] = 0;
        }
    } else {
        const float* srow = (const float*)src + ((size_t)l * K + k0 + kk) * N + n0;
        #pragma unroll
        for (int i = 0; i < 4; i++) {
            const int c = q * 4 + i * 16;
            const float4 v4 = *(const float4*)(srow + c);
            const float vv[4] = { v4.x, v4.y, v4.z, v4.w };
            #pragma unroll
            for (int j = 0; j < 4; j++) {
                const unsigned short h = f2bf_rn(vv[j]);
                sH[kk * 72 + c + j] = h;
                sL[kk * 72 + c + j] = f2bf_rn(vv[j] - bfb2f(h));
            }
        }
    }
    __syncthreads();
    // write: per unit (n, k-octet), b128 stores (coalesced 128B per 8 lanes)
    for (int u = tid; u < 512; u += 256) {
        const int n = u >> 3, k8 = (u & 7) * 8;
        u16x8 hh, ll;
        #pragma unroll
        for (int j = 0; j < 8; j++) {
            hh[j] = sH[(k8 + j) * 72 + n];
            ll[j] = sL[(k8 + j) * 72 + n];
        }
        unsigned short* dh = dst + ((size_t)l * N + n0 + n) * K + k0 + k8;
        *(u16x8*)dh = hh;
        *(u16x8*)(dh + loPlane) = ll;
    }
}

// ---------------------------------------------------------------- unified MFMA GEMM
// C[M=338 x N] = A[M x K] @ W + epilogue, bf16x3 split (fp32-grade accuracy).
// Tile 32(M) x 64(N), block 256 = 4 waves, wave = full 32 M x 16 N strip.
// mode 0: + bias -> out (xl/xr via z) ; z==0 also scatters xlT
// mode 1: relu(+bias) -> m1
// mode 2: + bias + residual -> x_next
__global__ __launch_bounds__(256) void k_gemm_mfma(
    const void* __restrict__ A, int a_raw, int K, int N,
    const unsigned short* __restrict__ wH0, const unsigned short* __restrict__ wL0,
    const unsigned short* __restrict__ wH1, const unsigned short* __restrict__ wL1,
    const void* __restrict__ bias0, const void* __restrict__ bias1, size_t oB,
    const void* __restrict__ res, int r_raw,
    float* __restrict__ out0, float* __restrict__ out1,
    float* __restrict__ xlT, int mode, const void* __restrict__ lng)
{
    __shared__ unsigned short sAh[32 * 40], sAl[32 * 40];
    __shared__ unsigned short sBh[64 * 40], sBl[64 * 40];
    const int isbf = sniff_bf(lng);
    const int z = blockIdx.z;
    const unsigned short* wH = z ? wH1 : wH0;
    const unsigned short* wL = z ? wL1 : wL0;
    const void* bias = z ? bias1 : bias0;
    float* out = z ? out1 : out0;
    const int a_bf = a_raw ? isbf : 0;
    const int tid = threadIdx.x;
    const int wave = tid >> 6, lane = tid & 63, l15 = lane & 15, g = lane >> 4;
    const int m0 = blockIdx.x * 32, n0 = blockIdx.y * 64;

    const int ar = tid >> 3, ak = (tid & 7) * 4;   // A staging: row, k-quad
    const int bn = tid >> 2, boct = tid & 3;       // B staging: col, k-octet

    f32x4 acc0 = {0.f, 0.f, 0.f, 0.f};
    f32x4 acc1 = {0.f, 0.f, 0.f, 0.f};
    const float* Af = (const float*)A;

    for (int k0 = 0; k0 < K; k0 += 32) {
        // A quad (global, guarded)
        unsigned short h4[4] = {0, 0, 0, 0}, l4[4] = {0, 0, 0, 0};
        {
            const int grow = m0 + ar;
            if (grow < NNTOT) {
                const size_t ai = (size_t)grow * K + k0 + ak;
                if (a_bf) {
                    const int2 w = *(const int2*)((const bf16*)A + ai);
                    h4[0] = (unsigned short)(w.x & 0xFFFF);
                    h4[1] = (unsigned short)(((unsigned)w.x) >> 16);
                    h4[2] = (unsigned short)(w.y & 0xFFFF);
                    h4[3] = (unsigned short)(((unsigned)w.y) >> 16);
                } else {
                    const float4 t = *(const float4*)(Af + ai);
                    const float vv[4] = { t.x, t.y, t.z, t.w };
                    #pragma unroll
                    for (int j = 0; j < 4; j++) {
                        h4[j] = f2bf_rn(vv[j]);
                        l4[j] = f2bf_rn(vv[j] - bfb2f(h4[j]));
                    }
                }
            }
        }
        // B octet (global, pre-transposed hi/lo planes)
        const size_t bi = (size_t)(n0 + bn) * K + k0 + boct * 8;
        const u16x8 bhv = *(const u16x8*)(wH + bi);
        const u16x8 blv = *(const u16x8*)(wL + bi);
        __syncthreads();
        {
            u16x4 ha, la;
            ha[0] = h4[0]; ha[1] = h4[1]; ha[2] = h4[2]; ha[3] = h4[3];
            la[0] = l4[0]; la[1] = l4[1]; la[2] = l4[2]; la[3] = l4[3];
            *(u16x4*)&sAh[ar * 40 + ak] = ha;
            *(u16x4*)&sAl[ar * 40 + ak] = la;
            *(u16x8*)&sBh[bn * 40 + boct * 8] = bhv;
            *(u16x8*)&sBl[bn * 40 + boct * 8] = blv;
        }
        __syncthreads();
        const bf16x8 a_h0 = *(const bf16x8*)&sAh[l15 * 40 + g * 8];
        const bf16x8 a_h1 = *(const bf16x8*)&sAh[(16 + l15) * 40 + g * 8];
        const bf16x8 a_l0 = *(const bf16x8*)&sAl[l15 * 40 + g * 8];
        const bf16x8 a_l1 = *(const bf16x8*)&sAl[(16 + l15) * 40 + g * 8];
        const bf16x8 b_h  = *(const bf16x8*)&sBh[(wave * 16 + l15) * 40 + g * 8];
        const bf16x8 b_l  = *(const bf16x8*)&sBl[(wave * 16 + l15) * 40 + g * 8];
        acc0 = __builtin_amdgcn_mfma_f32_16x16x32_bf16(a_h0, b_h, acc0, 0, 0, 0);
        acc1 = __builtin_amdgcn_mfma_f32_16x16x32_bf16(a_h1, b_h, acc1, 0, 0, 0);
        acc0 = __builtin_amdgcn_mfma_f32_16x16x32_bf16(a_l0, b_h, acc0, 0, 0, 0);
        acc1 = __builtin_amdgcn_mfma_f32_16x16x32_bf16(a_l1, b_h, acc1, 0, 0, 0);
        acc0 = __builtin_amdgcn_mfma_f32_16x16x32_bf16(a_h0, b_l, acc0, 0, 0, 0);
        acc1 = __builtin_amdgcn_mfma_f32_16x16x32_bf16(a_h1, b_l, acc1, 0, 0, 0);
    }

    // epilogue: row = m0 + mi*16 + g*4 + r, col = n0 + wave*16 + l15
    const int col = n0 + wave * 16 + l15;
    const float bv = ldm(bias, oB + col, isbf);
    #pragma unroll
    for (int mi = 0; mi < 2; mi++) {
        const f32x4 a = mi ? acc1 : acc0;
        #pragma unroll
        for (int r = 0; r < 4; r++) {
            const int row = m0 + mi * 16 + g * 4 + r;
            if (row >= NNTOT) continue;
            float v = a[r] + bv;
            if (mode == 1) v = fmaxf(v, 0.f);
            if (mode == 2) v += ldm(res, (size_t)row * N + col, r_raw ? isbf : 0);
            out[(size_t)row * N + col] = v;
            if (mode == 0 && z == 0) {
                const int hh = col >> 8, cc = col & 255;
                const int gg = (row >= NNODES) ? 1 : 0;
                const int ss = row - gg * NNODES;
                xlT[((size_t)(gg * NH + hh) * CH + cc) * SPAD + ss] = v;
            }
        }
    }
}

// ---------------------------------------------------------------- B: logits + softmax
// grid (85, NH, 2): block owns 2 targets for one (g,h). xlT staged to LDS in
// 32ch x 176src chunks (contiguous float4 copies); channel loop all-LDS.
// Writes alphaR[(g*4+h)*169 + d][s] rows (coalesced), head-mean 0.25/z folded.
__global__ __launch_bounds__(192) void k_logits_sm(
    const float* __restrict__ xlT, const float* __restrict__ xr,
    const void* __restrict__ att, size_t oA,
    float* __restrict__ alphaR, const void* __restrict__ lng)
{
    __shared__ float s_att[CH];
    __shared__ float s_xr[2 * CH];
    __shared__ float s_tile[32 * SPAD];
    __shared__ float s_log[2 * SPAD];
    const int isbf = sniff_bf(lng);
    const int g = blockIdx.z, h = blockIdx.y, d0 = blockIdx.x * 2;
    const int tid = threadIdx.x, lane = tid & 63, wv = tid >> 6;

    for (int idx = tid; idx < CH; idx += 192)
        s_att[idx] = ldm(att, oA + h * CH + idx, isbf);
    for (int idx = tid; idx < 2 * CH; idx += 192) {
        const int i = idx >> 8, c = idx & 255, d = d0 + i;
        s_xr[idx] = (d < NNODES)
            ? xr[(size_t)(g * NNODES + d) * (NH * CH) + h * CH + c] : 0.f;
    }

    float l0 = 0.f, l1 = 0.f;
    const int s = tid;
    const float4* src = (const float4*)(xlT + ((size_t)(g * NH + h) * CH) * SPAD);
    for (int ch = 0; ch < 8; ch++) {
        __syncthreads();
        #pragma unroll 2
        for (int i = tid; i < 32 * SPAD / 4; i += 192)
            ((float4*)s_tile)[i] = src[ch * (32 * SPAD / 4) + i];
        __syncthreads();
        if (s < NNODES) {
            const int cb = ch * 32;
            #pragma unroll
            for (int c = 0; c < 32; c++) {
                const float v = s_tile[c * SPAD + s];
                const float a = s_att[cb + c];
                l0 += a * lrelu(v + s_xr[cb + c]);
                l1 += a * lrelu(v + s_xr[CH + cb + c]);
            }
        }
    }
    if (s < NNODES) { s_log[s] = l0; s_log[SPAD + s] = l1; }
    __syncthreads();

    if (wv < 2) {
        const int d = d0 + wv;
        const float* row = s_log + wv * SPAD;
        const int s0 = lane, s1 = lane + 64, s2 = lane + 128;
        const float v0 = (s0 < NNODES && s0 != d) ? row[s0] : -1e30f;
        const float v1 = (s1 < NNODES && s1 != d) ? row[s1] : -1e30f;
        const float v2 = (s2 < NNODES && s2 != d) ? row[s2] : -1e30f;
        float mx = fmaxf(v0, fmaxf(v1, v2));
        mx = fmaxf(mx, __shfl_xor(mx, 32)); mx = fmaxf(mx, __shfl_xor(mx, 16));
        mx = fmaxf(mx, __shfl_xor(mx, 8));  mx = fmaxf(mx, __shfl_xor(mx, 4));
        mx = fmaxf(mx, __shfl_xor(mx, 2));  mx = fmaxf(mx, __shfl_xor(mx, 1));
        const float e0 = expf(v0 - mx), e1 = expf(v1 - mx), e2 = expf(v2 - mx);
        float zz = e0 + e1 + e2;
        zz += __shfl_xor(zz, 32); zz += __shfl_xor(zz, 16); zz += __shfl_xor(zz, 8);
        zz += __shfl_xor(zz, 4);  zz += __shfl_xor(zz, 2);  zz += __shfl_xor(zz, 1);
        const float sc = 0.25f / (zz + 1e-16f);
        if (d < NNODES) {
            float* arow = alphaR + ((size_t)(g * NH + h) * NNODES + d) * SPAD;
            if (s0 < NNODES) arow[s0] = e0 * sc;
            if (s1 < NNODES) arow[s1] = e1 * sc;
            if (s2 < NNODES) arow[s2] = e2 * sc;
        }
    }
}

// ---------------------------------------------------------------- C: aggregate as GEMM
// part[h][g*169+d][c] = sum_s alpha[d,s] * xl[s, h*256+c], per (g,h).
// grid (6 d-tiles of 32, 4 c-tiles of 64, 8 gh). K = sources, BK=32.
__global__ __launch_bounds__(256) void k_agg(
    const float* __restrict__ alphaR, const float* __restrict__ xl,
    float* __restrict__ part)
{
    __shared__ float s_a[32 * 33];
    __shared__ float s_x[32 * 64];
    const int gh = blockIdx.z, g = gh >> 2, h = gh & 3;
    const int d0 = blockIdx.x * 32, c0 = blockIdx.y * 64;
    const int tid = threadIdx.x;
    const int dr = (tid >> 4) * 2, cq = (tid & 15) * 4;
    const int sr = tid >> 3, sc4 = (tid & 7) * 4;
    const int xc8 = (tid & 7) * 8;

    float acc[2][4] = {{0.f,0.f,0.f,0.f},{0.f,0.f,0.f,0.f}};

    for (int s0 = 0; s0 < NNODES; s0 += 32) {
        __syncthreads();
        {   // alpha tile [32d][32s], zero-padded
            const int d = d0 + sr;
            const float* ap = alphaR + ((size_t)gh * NNODES + d) * SPAD + s0 + sc4;
            const int ok = (d < NNODES);
            s_a[sr * 33 + sc4 + 0] = (ok && s0 + sc4 + 0 < NNODES) ? ap[0] : 0.f;
            s_a[sr * 33 + sc4 + 1] = (ok && s0 + sc4 + 1 < NNODES) ? ap[1] : 0.f;
            s_a[sr * 33 + sc4 + 2] = (ok && s0 + sc4 + 2 < NNODES) ? ap[2] : 0.f;
            s_a[sr * 33 + sc4 + 3] = (ok && s0 + sc4 + 3 < NNODES) ? ap[3] : 0.f;
        }
        {   // x tile [32s][64c]
            const int sg = s0 + sr;
            if (sg < NNODES) {
                const float* xp = xl + (size_t)(g * NNODES + sg) * (NH * CH) + h * CH + c0 + xc8;
                *(float4*)&s_x[sr * 64 + xc8]     = *(const float4*)(xp);
                *(float4*)&s_x[sr * 64 + xc8 + 4] = *(const float4*)(xp + 4);
            } else {
                #pragma unroll
                for (int j = 0; j < 8; j++) s_x[sr * 64 + xc8 + j] = 0.f;
            }
        }
        __syncthreads();
        #pragma unroll
        for (int k = 0; k < 32; k++) {
            const float a0 = s_a[(dr + 0) * 33 + k];
            const float a1 = s_a[(dr + 1) * 33 + k];
            const float4 xv = *(const float4*)&s_x[k * 64 + cq];
            acc[0][0] += a0 * xv.x; acc[0][1] += a0 * xv.y;
            acc[0][2] += a0 * xv.z; acc[0][3] += a0 * xv.w;
            acc[1][0] += a1 * xv.x; acc[1][1] += a1 * xv.y;
            acc[1][2] += a1 * xv.z; acc[1][3] += a1 * xv.w;
        }
    }
    #pragma unroll
    for (int i = 0; i < 2; i++) {
        const int d = d0 + dr + i;
        if (d >= NNODES) continue;
        float4 v;
        v.x = acc[i][0]; v.y = acc[i][1]; v.z = acc[i][2]; v.w = acc[i][3];
        *(float4*)(part + ((size_t)h * NNTOT + g * NNODES + d) * CH + c0 + cq) = v;
    }
}

// ---------------------------------------------------------------- D: head-sum + LN
__global__ __launch_bounds__(256) void k_ln(
    const float* __restrict__ part,
    const void* __restrict__ bias, size_t oB,
    const void* __restrict__ ln_g, size_t oG,
    const void* __restrict__ ln_b, size_t oBt,
    float* __restrict__ h_out, const void* __restrict__ lng)
{
    __shared__ float s_red[8];
    const int isbf = sniff_bf(lng);
    const int node = blockIdx.x, c = threadIdx.x;
    const int lane = c & 63, wv = c >> 6;

    float vch = part[((size_t)0 * NNTOT + node) * CH + c]
              + part[((size_t)1 * NNTOT + node) * CH + c]
              + part[((size_t)2 * NNTOT + node) * CH + c]
              + part[((size_t)3 * NNTOT + node) * CH + c]
              + ldm(bias, oB + c, isbf);

    float s1 = vch, s2 = vch * vch;
    s1 += __shfl_xor(s1, 32); s2 += __shfl_xor(s2, 32);
    s1 += __shfl_xor(s1, 16); s2 += __shfl_xor(s2, 16);
    s1 += __shfl_xor(s1, 8);  s2 += __shfl_xor(s2, 8);
    s1 += __shfl_xor(s1, 4);  s2 += __shfl_xor(s2, 4);
    s1 += __shfl_xor(s1, 2);  s2 += __shfl_xor(s2, 2);
    s1 += __shfl_xor(s1, 1);  s2 += __shfl_xor(s2, 1);
    if (lane == 0) { s_red[wv] = s1; s_red[4 + wv] = s2; }
    __syncthreads();
    const float S1 = s_red[0] + s_red[1] + s_red[2] + s_red[3];
    const float S2 = s_red[4] + s_red[5] + s_red[6] + s_red[7];
    const float mu  = S1 * (1.f / CH);
    const float var = S2 * (1.f / CH) - mu * mu;
    const float o = (vch - mu) * rsqrtf(var + LN_EPS) * ldm(ln_g, oG + c, isbf)
                  + ldm(ln_b, oBt + c, isbf);
    h_out[(size_t)node * CH + c] = o;
}

// ---------------------------------------------------------------- pool
__global__ __launch_bounds__(256) void k_pool(const float* __restrict__ x,
                                              void* __restrict__ out,
                                              const void* __restrict__ lng) {
    const int isbf = sniff_bf(lng);
    const int g = blockIdx.x, c = threadIdx.x;
    float s = 0.f;
    const float* p = x + (size_t)g * NNODES * CH + c;
    for (int n = 0; n < NNODES; n++) s += p[(size_t)n * CH];
    const float v = s * (1.f / NNODES);
    if (isbf) ((bf16*)out)[g * CH + c] = __float2bfloat16(v);
    else      ((float*)out)[g * CH + c] = v;
}

// ---------------------------------------------------------------- launch
extern "C" void kernel_launch(void* const* d_in, const int* in_sizes, int n_in,
                              void* d_out, int out_size, void* d_ws, size_t ws_size,
                              hipStream_t stream)
{
    const void* x_in = d_in[0];
    const void* Wl   = d_in[1];
    const void* bl   = d_in[2];
    const void* Wr   = d_in[3];
    const void* br   = d_in[4];
    const void* att  = d_in[5];
    const void* bias = d_in[6];
    const void* lng  = d_in[7];
    const void* lnb  = d_in[8];
    const void* W1   = d_in[9];
    const void* b1   = d_in[10];
    const void* W2   = d_in[11];
    const void* b2   = d_in[12];

    float* ws     = (float*)d_ws;
    float* xl     = ws;                                      // 338*1024
    float* xr     = xl + (size_t)NNTOT * NH * CH;            // 338*1024
    float* xlT    = xr + (size_t)NNTOT * NH * CH;            // 2*4*256*176
    float* alphaR = xlT + (size_t)2 * NH * CH * SPAD;        // 2*4*169*176
    float* part   = alphaR + (size_t)2 * NH * NNODES * SPAD; // 4*338*256
    float* h_ln   = part + (size_t)NH * NNTOT * CH;          // 338*256
    float* m1     = h_ln + (size_t)NNTOT * CH;               // 338*512
    float* xa     = m1 + (size_t)NNTOT * 2 * CH;             // 338*256
    float* xb     = xa + (size_t)NNTOT * CH;                 // 338*256

    // bf16 hi/lo transposed weight planes ([L][N][K] bits), after float region
    unsigned short* wbt = (unsigned short*)(xb + (size_t)NNTOT * CH);
    const size_t pLR = (size_t)NL * (NH * CH) * CH;   // 3*1024*256 per plane
    const size_t pM  = (size_t)NL * (2 * CH) * CH;    // 3*512*256  per plane
    unsigned short* wlT = wbt;
    unsigned short* wrT = wlT + 2 * pLR;
    unsigned short* w1T = wrT + 2 * pLR;
    unsigned short* w2T = w1T + 2 * pM;
    const size_t lyLR = (size_t)(NH * CH) * CH;       // per-layer slice 1024*256
    const size_t lyM  = (size_t)(2 * CH) * CH;        // per-layer slice 512*256

    const size_t sB  = NH * CH;
    const size_t sC  = CH;
    const size_t sB1 = 2 * CH;

    const void* x_l[3] = { x_in, xa, xb };
    float*      x_o[3] = { xa, xb, xa };

    k_wprep<<<dim3(576), 256, 0, stream>>>(Wl, Wr, W1, W2, wlT, wrT, w1T, w2T, lng);

    for (int l = 0; l < NL; l++) {
        const int israw = (l == 0);
        // xl = x@Wl+bl (+xlT scatter), xr = x@Wr+br
        k_gemm_mfma<<<dim3(11, 16, 2), 256, 0, stream>>>(
            x_l[l], israw, CH, NH * CH,
            wlT + l * lyLR, wlT + pLR + l * lyLR,
            wrT + l * lyLR, wrT + pLR + l * lyLR,
            bl, br, (size_t)l * sB,
            nullptr, 0,
            xl, xr, xlT, 0, lng);
        k_logits_sm<<<dim3(85, NH, 2), 192, 0, stream>>>(
            xlT, xr, att, (size_t)l * sB, alphaR, lng);
        k_agg<<<dim3(6, 4, 8), 256, 0, stream>>>(alphaR, xl, part);
        k_ln<<<dim3(NNTOT), 256, 0, stream>>>(
            part, bias, (size_t)l * sC, lng, (size_t)l * sC, lnb, (size_t)l * sC,
            h_ln, lng);
        // m1 = relu(h_ln@W1+b1)
        k_gemm_mfma<<<dim3(11, 8, 1), 256, 0, stream>>>(
            h_ln, 0, CH, 2 * CH,
            w1T + l * lyM, w1T + pM + l * lyM,
            w1T + l * lyM, w1T + pM + l * lyM,
            b1, b1, (size_t)l * sB1,
            nullptr, 0,
            m1, m1, nullptr, 1, lng);
        // x_next = x + m1@W2 + b2
        k_gemm_mfma<<<dim3(11, 4, 1), 256, 0, stream>>>(
            m1, 0, 2 * CH, CH,
            w2T + l * lyM, w2T + pM + l * lyM,
            w2T + l * lyM, w2T + pM + l * lyM,
            b2, b2, (size_t)l * sC,
            x_l[l], israw,
            x_o[l], x_o[l], nullptr, 2, lng);
    }

    k_pool<<<dim3(2), 256, 0, stream>>>(xa, d_out, lng);
}